// Round 2
// baseline (153.179 us; speedup 1.0000x reference)
//
#include <hip/hip_runtime.h>
#include <hip/hip_cooperative_groups.h>
#include <math.h>

namespace cg = cooperative_groups;

typedef float v2f __attribute__((ext_vector_type(2)));

#define N_BOX   256
#define M_PTS   512
#define S_SPLIT 4                    // m2-range splits per box
#define BLK     256                  // 4 waves per block
#define M2_PER  (M_PTS / S_SPLIT)    // 128 m2 per block
#define GRID    (N_BOX * S_SPLIT)    // 1024 blocks -> 4 blocks/CU co-resident

// Single cooperative dispatch: fused precompute + pair loop + grid-wide reduce.
// Rationale: round0->round1 A/B showed total time is dominated by per-dispatch
// overhead (~8us/launch), not kernel throughput. One launch removes ~2 gaps +
// the P1/P2 global round-trip.
__global__ __launch_bounds__(BLK, 4) void loss_fused(
    const float* __restrict__ pred,    // (N,5)
    const float* __restrict__ target,  // (N,5)
    const float* __restrict__ mask,    // (N,M,2)
    const float* __restrict__ gradx,   // (N,M)
    const float* __restrict__ grady,   // (N,M)
    const float* __restrict__ offset,  // (N,2)
    float* __restrict__ part,          // (GRID,) scratch in ws
    float* __restrict__ out)           // scalar result
{
    __shared__ float4 sP[M2_PER];
    __shared__ float  sW[4];

    const int n = blockIdx.x >> 2;
    const int s = blockIdx.x & 3;
    const int t = threadIdx.x;

    // ---- box scalars (uniform per block; redundant per thread — cheap) ----
    const float offx = offset[n * 2 + 0];
    const float offy = offset[n * 2 + 1];
    const float px = pred[n * 5 + 0] - offx;
    const float py = pred[n * 5 + 1] - offy;
    const float pw = pred[n * 5 + 2];
    const float ph = pred[n * 5 + 3];
    const float pa = pred[n * 5 + 4];
    const float gx = target[n * 5 + 0] - offx;
    const float gy = target[n * 5 + 1] - offy;
    const float gw = target[n * 5 + 2];
    const float gh = target[n * 5 + 3];
    const float ga = target[n * 5 + 4];

    float sinpa, cospa, singa, cosga;
    sincosf(pa, &sinpa, &cospa);
    sincosf(ga, &singa, &cosga);

    const float THETA2   = 400.0f;
    const float LOG2E    = 1.4426950408889634f;
    const float c1       = LOG2E / (2.0f * THETA2 * THETA2);
    const float rs       = sqrtf(c1);                 // fold exp2 scale into coords
    const float inv_norm = 1.0f / (2.0f * (float)M_PI * THETA2);

    const float pwg = pw / gw, phg = ph / gh;
    const float cwx = pwg * cospa, swx = pwg * sinpa;
    const float chx = phg * cospa, shx = phg * sinpa;
    const float absinga = fabsf(singa);
    const float kA  = 15.0f * LOG2E / gw;
    const float kH  = 15.0f * LOG2E / gh;
    const float kB  = 15.0f * LOG2E;
    const float pxrs = px * rs, pyrs = py * rs;
    const bool  gaPos = (ga > 0.0f), gaNeg = (ga < 0.0f);

    const float2* mask2 = (const float2*)mask;
    const size_t  base  = (size_t)n * M_PTS;

    // ---- phase 2 pack: threads t<128 own m2 = s*128 + t (wrap not needed) ----
    if (t < M2_PER) {
        const int m = s * M2_PER + t;
        const float2 mp = mask2[base + m];
        const float dx = mp.x - gx;
        const float dy = mp.y - gy;
        const float u = singa * dy - cosga * dx;     // d*cos(beta)
        const float v = -(cosga * dy + singa * dx);  // d*sin(beta)
        const float au = fabsf(u), av = fabsf(v);    // d_w, d_h
        // (1-sig(x))(1-sig(y)) = 1/((1+e^x)(1+e^y)), folded with gaussian norm
        const float eA = __builtin_amdgcn_exp2f(fmaf(au, kA, -kB));
        const float eB = __builtin_amdgcn_exp2f(fmaf(av, kH, -kB));
        const float B  = inv_norm / ((1.0f + eA) * (1.0f + eB));
        sP[t] = make_float4(mp.x * rs, mp.y * rs,
                            gradx[base + m] * B, grady[base + m] * B);
    }

    // ---- phase 1: rows t, t+256 (rotation identity, no acos/sincos) ----
    v2f Gx, Gy, gvx, gvy;
#pragma unroll
    for (int r = 0; r < 2; ++r) {
        const int m = t + (r << 8);
        const float2 mp = mask2[base + m];
        const float dx = mp.x - gx;
        const float dy = mp.y - gy;
        const float u = singa * dy - cosga * dx;
        const float v = -(cosga * dy + singa * dx);
        // wrap <=> |beta| > pi
        const bool sgaOk = gaPos ? (dy <= 0.0f) : (gaNeg ? (dy > 0.0f) : false);
        const bool wrap  = sgaOk && (dx > 0.0f) && (dx * absinga > fabsf(dy) * cosga);
        const float au = fabsf(u), av = fabsf(v);
        const float dws = (wrap || v > 0.0f) ? -au : au;
        const float dhs = (wrap || u > 0.0f) ? -av : av;
        const float gpx = dws * cwx - dhs * shx;
        const float gpy = dws * swx + dhs * chx;
        Gx[r]  = fmaf(gpx, rs, pxrs);                // pre-scaled gaussian center
        Gy[r]  = fmaf(gpy, rs, pyrs);
        gvx[r] = gradx[base + m];
        gvy[r] = grady[base + m];
    }
    __syncthreads();

    // ---- O(M*M) inner loop: LDS broadcast + v2f pair math + exp2 ----
    v2f accz = (v2f)0.0f, accw = (v2f)0.0f;
#pragma unroll 4
    for (int m2 = 0; m2 < M2_PER; ++m2) {
        const float4 p = sP[m2];                     // broadcast ds_read_b128
        v2f dgx = Gx - p.x;
        v2f dgy = Gy - p.y;
        v2f sa  = dgx * dgx + dgy * dgy;             // already scaled by c1
        v2f e;
        e.x = __builtin_amdgcn_exp2f(sa.x);
        e.y = __builtin_amdgcn_exp2f(sa.y);
        accz += e * p.z;
        accw += e * p.w;
    }

    // w-term factorization: sum w*e = gvx*sum(zB*e) + gvy*sum(wB*e)
    v2f tot = accz * gvx + accw * gvy;
    float acc = tot.x + tot.y;
#pragma unroll
    for (int off = 32; off > 0; off >>= 1)
        acc += __shfl_down(acc, off, 64);
    if ((t & 63) == 0) sW[t >> 6] = acc;
    __syncthreads();
    if (t == 0) part[blockIdx.x] = sW[0] + sW[1] + sW[2] + sW[3];

    cg::this_grid().sync();

    // ---- final reduce on block 0: 1024 partials = 256 float4 ----
    if (blockIdx.x == 0) {
        const float4* p4 = (const float4*)part;
        const float4 a = p4[t];
        float acc2 = (a.x + a.y) + (a.z + a.w);
#pragma unroll
        for (int off = 32; off > 0; off >>= 1)
            acc2 += __shfl_down(acc2, off, 64);
        __syncthreads();                 // guard sW reuse
        if ((t & 63) == 0) sW[t >> 6] = acc2;
        __syncthreads();
        if (t == 0) {
            const float scale = 1.0f / ((float)N_BOX * (float)M_PTS * (float)M_PTS);
            out[0] = (sW[0] + sW[1] + sW[2] + sW[3]) * scale;
        }
    }
}

extern "C" void kernel_launch(void* const* d_in, const int* in_sizes, int n_in,
                              void* d_out, int out_size, void* d_ws, size_t ws_size,
                              hipStream_t stream) {
    const float* pred   = (const float*)d_in[0];
    const float* target = (const float*)d_in[1];
    const float* mask   = (const float*)d_in[2];
    const float* gradx  = (const float*)d_in[3];
    const float* grady  = (const float*)d_in[4];
    const float* offset = (const float*)d_in[5];
    float* out  = (float*)d_out;
    float* part = (float*)d_ws;          // 4 KB of scratch, fully overwritten

    void* kargs[] = { (void*)&pred, (void*)&target, (void*)&mask, (void*)&gradx,
                      (void*)&grady, (void*)&offset, (void*)&part, (void*)&out };
    hipLaunchCooperativeKernel((const void*)loss_fused, dim3(GRID), dim3(BLK),
                               kargs, 0, stream);
}

// Round 3
// 106.075 us; speedup vs baseline: 1.4441x; 1.4441x over previous
//
#include <hip/hip_runtime.h>
#include <math.h>

typedef float v2f __attribute__((ext_vector_type(2)));

#define N_BOX   256
#define M_PTS   512
#define S_SPLIT 8                    // m2-range splits per box
#define BLK     256                  // 4 waves per block
#define M2_PER  (M_PTS / S_SPLIT)    // 64 m2 per block
#define GRID    (N_BOX * S_SPLIT)    // 2048 blocks -> 8 blocks/CU, 8 waves/SIMD
#define LEAF_BLKS 64                 // blocks per leaf counter
#define N_LEAF    (GRID / LEAF_BLKS) // 32 leaf counters

// ws layout (dword indices):
//   [0,    2048)  part[] : per-block partials
//   [4096, ...)   leaf counters: ctr g at dword 4096+g*32 (128B slots),
//                 poison sibling at +4 dwords (same 16B pattern phase)
//   dword 5120    master counter, sibling at 5124
//
// Single plain dispatch. Final reduce by the LAST block to increment the
// master counter. ws is re-poisoned with an UNKNOWN uniform value each
// iteration, so counters are calibrated against an untouched sibling word
// and the "last" test is modulo GRID ((old-poison)&(G-1) == G-1), which is
// also robust if a re-poison is ever skipped.
__global__ __launch_bounds__(BLK, 8) void loss_onepass(
    const float* __restrict__ pred,    // (N,5)
    const float* __restrict__ target,  // (N,5)
    const float* __restrict__ mask,    // (N,M,2)
    const float* __restrict__ gradx,   // (N,M)
    const float* __restrict__ grady,   // (N,M)
    const float* __restrict__ offset,  // (N,2)
    float* __restrict__ ws,            // workspace base
    float* __restrict__ out)           // scalar result
{
    __shared__ float4 sP[M2_PER];
    __shared__ float  sW[4];
    __shared__ int    sLast;

    const int bid = blockIdx.x;
    const int n = bid >> 3;
    const int s = bid & 7;
    const int t = threadIdx.x;

    // ---- box scalars (uniform per block) ----
    const float offx = offset[n * 2 + 0];
    const float offy = offset[n * 2 + 1];
    const float px = pred[n * 5 + 0] - offx;
    const float py = pred[n * 5 + 1] - offy;
    const float pw = pred[n * 5 + 2];
    const float ph = pred[n * 5 + 3];
    const float pa = pred[n * 5 + 4];
    const float gx = target[n * 5 + 0] - offx;
    const float gy = target[n * 5 + 1] - offy;
    const float gw = target[n * 5 + 2];
    const float gh = target[n * 5 + 3];
    const float ga = target[n * 5 + 4];

    float sinpa, cospa, singa, cosga;
    sincosf(pa, &sinpa, &cospa);
    sincosf(ga, &singa, &cosga);

    const float THETA2   = 400.0f;
    const float LOG2E    = 1.4426950408889634f;
    const float c1       = LOG2E / (2.0f * THETA2 * THETA2);
    const float rs       = sqrtf(c1);                 // fold exp2 scale into coords
    const float inv_norm = 1.0f / (2.0f * (float)M_PI * THETA2);

    const float pwg = pw / gw, phg = ph / gh;
    const float cwx = pwg * cospa, swx = pwg * sinpa;
    const float chx = phg * cospa, shx = phg * sinpa;
    const float absinga = fabsf(singa);
    const float kA  = 15.0f * LOG2E / gw;
    const float kH  = 15.0f * LOG2E / gh;
    const float kB  = 15.0f * LOG2E;
    const float pxrs = px * rs, pyrs = py * rs;
    const bool  gaPos = (ga > 0.0f), gaNeg = (ga < 0.0f);

    const float2* mask2 = (const float2*)mask;
    const size_t  base  = (size_t)n * M_PTS;

    // ---- phase 2 pack: threads t<64 own m2 = s*64 + t ----
    if (t < M2_PER) {
        const int m = s * M2_PER + t;
        const float2 mp = mask2[base + m];
        const float dx = mp.x - gx;
        const float dy = mp.y - gy;
        const float u = singa * dy - cosga * dx;     // d*cos(beta)
        const float v = -(cosga * dy + singa * dx);  // d*sin(beta)
        const float au = fabsf(u), av = fabsf(v);    // d_w, d_h
        const float eA = __builtin_amdgcn_exp2f(fmaf(au, kA, -kB));
        const float eB = __builtin_amdgcn_exp2f(fmaf(av, kH, -kB));
        const float B  = inv_norm / ((1.0f + eA) * (1.0f + eB));
        sP[t] = make_float4(mp.x * rs, mp.y * rs,
                            gradx[base + m] * B, grady[base + m] * B);
    }

    // ---- phase 1: rows t, t+256 (rotation identity, no acos/sincos) ----
    v2f Gx, Gy, gvx, gvy;
#pragma unroll
    for (int r = 0; r < 2; ++r) {
        const int m = t + (r << 8);
        const float2 mp = mask2[base + m];
        const float dx = mp.x - gx;
        const float dy = mp.y - gy;
        const float u = singa * dy - cosga * dx;
        const float v = -(cosga * dy + singa * dx);
        const bool sgaOk = gaPos ? (dy <= 0.0f) : (gaNeg ? (dy > 0.0f) : false);
        const bool wrap  = sgaOk && (dx > 0.0f) && (dx * absinga > fabsf(dy) * cosga);
        const float au = fabsf(u), av = fabsf(v);
        const float dws = (wrap || v > 0.0f) ? -au : au;
        const float dhs = (wrap || u > 0.0f) ? -av : av;
        const float gpx = dws * cwx - dhs * shx;
        const float gpy = dws * swx + dhs * chx;
        Gx[r]  = fmaf(gpx, rs, pxrs);
        Gy[r]  = fmaf(gpy, rs, pyrs);
        gvx[r] = gradx[base + m];
        gvy[r] = grady[base + m];
    }
    __syncthreads();

    // ---- O(M*M) inner loop: LDS broadcast + v2f pair math + exp2 ----
    v2f accz = (v2f)0.0f, accw = (v2f)0.0f;
#pragma unroll 4
    for (int m2 = 0; m2 < M2_PER; ++m2) {
        const float4 p = sP[m2];                     // broadcast ds_read_b128
        v2f dgx = Gx - p.x;
        v2f dgy = Gy - p.y;
        v2f sa  = dgx * dgx + dgy * dgy;             // pre-scaled by c1
        v2f e;
        e.x = __builtin_amdgcn_exp2f(sa.x);
        e.y = __builtin_amdgcn_exp2f(sa.y);
        accz += e * p.z;
        accw += e * p.w;
    }

    // w-term factorization: sum w*e = gvx*sum(zB*e) + gvy*sum(wB*e)
    v2f tot = accz * gvx + accw * gvy;
    float acc = tot.x + tot.y;
#pragma unroll
    for (int off = 32; off > 0; off >>= 1)
        acc += __shfl_down(acc, off, 64);
    if ((t & 63) == 0) sW[t >> 6] = acc;
    __syncthreads();

    // ---- completion protocol (thread 0 only) ----
    float* part = ws;                                  // 2048 floats
    uint*  ctrL = (uint*)ws + 4096;                    // 32 slots * 32 dwords
    uint*  ctrM = (uint*)ws + 5120;
    if (t == 0) {
        const float blockSum = sW[0] + sW[1] + sW[2] + sW[3];
        __hip_atomic_store(&part[bid], blockSum,
                           __ATOMIC_RELAXED, __HIP_MEMORY_SCOPE_AGENT);
        int last = 0;
        const int  g   = bid >> 6;                     // leaf group, 64 blocks
        uint* slot = ctrL + g * 32;
        const uint pL  = slot[4];                      // poison calibration
        const uint oL  = __hip_atomic_fetch_add(slot, 1u,
                             __ATOMIC_ACQ_REL, __HIP_MEMORY_SCOPE_AGENT);
        if (((oL - pL) & (LEAF_BLKS - 1)) == (LEAF_BLKS - 1)) {
            const uint pM = ctrM[4];
            const uint oM = __hip_atomic_fetch_add(ctrM, 1u,
                                __ATOMIC_ACQ_REL, __HIP_MEMORY_SCOPE_AGENT);
            if (((oM - pM) & (N_LEAF - 1)) == (N_LEAF - 1)) last = 1;
        }
        sLast = last;
    }
    __syncthreads();

    // ---- final reduce by the single last-arriving block ----
    if (sLast) {
        float a2 = 0.0f;
#pragma unroll
        for (int i = 0; i < 8; ++i)
            a2 += __hip_atomic_load(&part[t + (i << 8)],
                      __ATOMIC_RELAXED, __HIP_MEMORY_SCOPE_AGENT);
#pragma unroll
        for (int off = 32; off > 0; off >>= 1)
            a2 += __shfl_down(a2, off, 64);
        if ((t & 63) == 0) sW[t >> 6] = a2;
        __syncthreads();
        if (t == 0) {
            const float scale = 1.0f / ((float)N_BOX * (float)M_PTS * (float)M_PTS);
            out[0] = (sW[0] + sW[1] + sW[2] + sW[3]) * scale;
        }
    }
}

extern "C" void kernel_launch(void* const* d_in, const int* in_sizes, int n_in,
                              void* d_out, int out_size, void* d_ws, size_t ws_size,
                              hipStream_t stream) {
    const float* pred   = (const float*)d_in[0];
    const float* target = (const float*)d_in[1];
    const float* mask   = (const float*)d_in[2];
    const float* gradx  = (const float*)d_in[3];
    const float* grady  = (const float*)d_in[4];
    const float* offset = (const float*)d_in[5];
    float* out = (float*)d_out;
    float* ws  = (float*)d_ws;

    hipLaunchKernelGGL(loss_onepass, dim3(GRID), dim3(BLK), 0, stream,
                       pred, target, mask, gradx, grady, offset, ws, out);
}

// Round 4
// 84.674 us; speedup vs baseline: 1.8090x; 1.2527x over previous
//
#include <hip/hip_runtime.h>
#include <math.h>

typedef float v2f __attribute__((ext_vector_type(2)));

#define N_BOX   256
#define M_PTS   512
#define S_SPLIT 8                    // m2-range splits per box
#define BLK     256                  // 4 waves per block
#define M2_PER  (M_PTS / S_SPLIT)    // 64 m2 per block
#define GRID    (N_BOX * S_SPLIT)    // 2048 blocks -> 8 blocks/CU, 8 waves/SIMD
#define LEAF_BLKS 64                 // blocks per leaf counter
#define N_LEAF    (GRID / LEAF_BLKS) // 32 leaf counters

// ws layout (dword indices):
//   [0,    2048)  part[] : per-block partials (relaxed agent atomic = sc1 write-through)
//   [4096, 5120)  leaf counters: ctr g at dword 4096+g*32 (128B slots),
//                 poison-calibration sibling at +4 dwords
//   dword 5120    master counter, sibling at 5124
//
// Completion protocol is FENCE-FREE (round-3 A/B showed ACQ_REL fences --
// buffer_wbl2/buffer_inv per block -- cost ~34us):
//   relaxed atomic store part (write-through to coherent point)
//   s_waitcnt vmcnt(0)          -- store ACKed at LLC before counter bump
//   relaxed fetch_add leaf      -- same-line RMWs serialize at LLC, so
//                                  count==63 happens-after all 64 stores
//   relaxed fetch_add master (leaf winners only), last block reduces via
//   relaxed atomic loads (sc1, read at LLC).
__global__ __launch_bounds__(BLK, 8) void loss_onepass(
    const float* __restrict__ pred,    // (N,5)
    const float* __restrict__ target,  // (N,5)
    const float* __restrict__ mask,    // (N,M,2)
    const float* __restrict__ gradx,   // (N,M)
    const float* __restrict__ grady,   // (N,M)
    const float* __restrict__ offset,  // (N,2)
    float* __restrict__ ws,            // workspace base
    float* __restrict__ out)           // scalar result
{
    __shared__ float4 sP[M2_PER];
    __shared__ float  sW[4];
    __shared__ int    sLast;

    const int bid = blockIdx.x;
    const int n = bid >> 3;
    const int s = bid & 7;
    const int t = threadIdx.x;

    // ---- box scalars (uniform per block) ----
    const float offx = offset[n * 2 + 0];
    const float offy = offset[n * 2 + 1];
    const float px = pred[n * 5 + 0] - offx;
    const float py = pred[n * 5 + 1] - offy;
    const float pw = pred[n * 5 + 2];
    const float ph = pred[n * 5 + 3];
    const float pa = pred[n * 5 + 4];
    const float gx = target[n * 5 + 0] - offx;
    const float gy = target[n * 5 + 1] - offy;
    const float gw = target[n * 5 + 2];
    const float gh = target[n * 5 + 3];
    const float ga = target[n * 5 + 4];

    float sinpa, cospa, singa, cosga;
    sincosf(pa, &sinpa, &cospa);
    sincosf(ga, &singa, &cosga);

    const float THETA2   = 400.0f;
    const float LOG2E    = 1.4426950408889634f;
    const float c1       = LOG2E / (2.0f * THETA2 * THETA2);
    const float rs       = sqrtf(c1);                 // fold exp2 scale into coords
    const float inv_norm = 1.0f / (2.0f * (float)M_PI * THETA2);

    const float pwg = pw / gw, phg = ph / gh;
    const float cwx = pwg * cospa, swx = pwg * sinpa;
    const float chx = phg * cospa, shx = phg * sinpa;
    const float absinga = fabsf(singa);
    const float kA  = 15.0f * LOG2E / gw;
    const float kH  = 15.0f * LOG2E / gh;
    const float kB  = 15.0f * LOG2E;
    const float pxrs = px * rs, pyrs = py * rs;
    const bool  gaPos = (ga > 0.0f), gaNeg = (ga < 0.0f);

    const float2* mask2 = (const float2*)mask;
    const size_t  base  = (size_t)n * M_PTS;

    // ---- phase 2 pack: threads t<64 own m2 = s*64 + t ----
    if (t < M2_PER) {
        const int m = s * M2_PER + t;
        const float2 mp = mask2[base + m];
        const float dx = mp.x - gx;
        const float dy = mp.y - gy;
        const float u = singa * dy - cosga * dx;     // d*cos(beta)
        const float v = -(cosga * dy + singa * dx);  // d*sin(beta)
        const float au = fabsf(u), av = fabsf(v);    // d_w, d_h
        const float eA = __builtin_amdgcn_exp2f(fmaf(au, kA, -kB));
        const float eB = __builtin_amdgcn_exp2f(fmaf(av, kH, -kB));
        const float B  = inv_norm / ((1.0f + eA) * (1.0f + eB));
        sP[t] = make_float4(mp.x * rs, mp.y * rs,
                            gradx[base + m] * B, grady[base + m] * B);
    }

    // ---- phase 1: rows t, t+256 (rotation identity, no acos/sincos) ----
    v2f Gx, Gy, gvx, gvy;
#pragma unroll
    for (int r = 0; r < 2; ++r) {
        const int m = t + (r << 8);
        const float2 mp = mask2[base + m];
        const float dx = mp.x - gx;
        const float dy = mp.y - gy;
        const float u = singa * dy - cosga * dx;
        const float v = -(cosga * dy + singa * dx);
        const bool sgaOk = gaPos ? (dy <= 0.0f) : (gaNeg ? (dy > 0.0f) : false);
        const bool wrap  = sgaOk && (dx > 0.0f) && (dx * absinga > fabsf(dy) * cosga);
        const float au = fabsf(u), av = fabsf(v);
        const float dws = (wrap || v > 0.0f) ? -au : au;
        const float dhs = (wrap || u > 0.0f) ? -av : av;
        const float gpx = dws * cwx - dhs * shx;
        const float gpy = dws * swx + dhs * chx;
        Gx[r]  = fmaf(gpx, rs, pxrs);
        Gy[r]  = fmaf(gpy, rs, pyrs);
        gvx[r] = gradx[base + m];
        gvy[r] = grady[base + m];
    }
    __syncthreads();

    // ---- O(M*M) inner loop: LDS broadcast + v2f pair math + exp2 ----
    v2f accz = (v2f)0.0f, accw = (v2f)0.0f;
#pragma unroll 4
    for (int m2 = 0; m2 < M2_PER; ++m2) {
        const float4 p = sP[m2];                     // broadcast ds_read_b128
        v2f dgx = Gx - p.x;
        v2f dgy = Gy - p.y;
        v2f sa  = dgx * dgx + dgy * dgy;             // pre-scaled by c1
        v2f e;
        e.x = __builtin_amdgcn_exp2f(sa.x);
        e.y = __builtin_amdgcn_exp2f(sa.y);
        accz += e * p.z;
        accw += e * p.w;
    }

    // w-term factorization: sum w*e = gvx*sum(zB*e) + gvy*sum(wB*e)
    v2f tot = accz * gvx + accw * gvy;
    float acc = tot.x + tot.y;
#pragma unroll
    for (int off = 32; off > 0; off >>= 1)
        acc += __shfl_down(acc, off, 64);
    if ((t & 63) == 0) sW[t >> 6] = acc;
    __syncthreads();

    // ---- fence-free completion protocol (thread 0 only) ----
    float* part = ws;                                  // 2048 floats
    unsigned int* ctrL = (unsigned int*)ws + 4096;     // 32 slots * 32 dwords
    unsigned int* ctrM = (unsigned int*)ws + 5120;
    if (t == 0) {
        const float blockSum = sW[0] + sW[1] + sW[2] + sW[3];
        __hip_atomic_store(&part[bid], blockSum,
                           __ATOMIC_RELAXED, __HIP_MEMORY_SCOPE_AGENT);
        // store is write-through (sc1); wait for its ACK at the coherent
        // point so the counter bump below happens-after it. No buffer_wbl2.
        asm volatile("s_waitcnt vmcnt(0)" ::: "memory");
        int last = 0;
        const int g = bid >> 6;                        // leaf group, 64 blocks
        unsigned int* slot = ctrL + g * 32;
        const unsigned int pL = slot[4];               // poison calibration
        const unsigned int oL = __hip_atomic_fetch_add(slot, 1u,
                                    __ATOMIC_RELAXED, __HIP_MEMORY_SCOPE_AGENT);
        if (((oL - pL) & (LEAF_BLKS - 1)) == (LEAF_BLKS - 1)) {
            const unsigned int pM = ctrM[4];
            const unsigned int oM = __hip_atomic_fetch_add(ctrM, 1u,
                                        __ATOMIC_RELAXED, __HIP_MEMORY_SCOPE_AGENT);
            if (((oM - pM) & (N_LEAF - 1)) == (N_LEAF - 1)) last = 1;
        }
        sLast = last;
    }
    __syncthreads();

    // ---- final reduce by the single last-arriving block ----
    if (sLast) {
        float a2 = 0.0f;
#pragma unroll
        for (int i = 0; i < 8; ++i)
            a2 += __hip_atomic_load(&part[t + (i << 8)],
                      __ATOMIC_RELAXED, __HIP_MEMORY_SCOPE_AGENT);
#pragma unroll
        for (int off = 32; off > 0; off >>= 1)
            a2 += __shfl_down(a2, off, 64);
        if ((t & 63) == 0) sW[t >> 6] = a2;
        __syncthreads();
        if (t == 0) {
            const float scale = 1.0f / ((float)N_BOX * (float)M_PTS * (float)M_PTS);
            out[0] = (sW[0] + sW[1] + sW[2] + sW[3]) * scale;
        }
    }
}

extern "C" void kernel_launch(void* const* d_in, const int* in_sizes, int n_in,
                              void* d_out, int out_size, void* d_ws, size_t ws_size,
                              hipStream_t stream) {
    const float* pred   = (const float*)d_in[0];
    const float* target = (const float*)d_in[1];
    const float* mask   = (const float*)d_in[2];
    const float* gradx  = (const float*)d_in[3];
    const float* grady  = (const float*)d_in[4];
    const float* offset = (const float*)d_in[5];
    float* out = (float*)d_out;
    float* ws  = (float*)d_ws;

    hipLaunchKernelGGL(loss_onepass, dim3(GRID), dim3(BLK), 0, stream,
                       pred, target, mask, gradx, grady, offset, ws, out);
}